// Round 13
// baseline (608.397 us; speedup 1.0000x reference)
//
#include <hip/hip_runtime.h>
#include <math.h>

#define H_DIM 2880
#define E_NUM 32
#define TOPK 4
#define TT 32        // tokens per block -> grid 512, 2 blocks/CU
#define KW 64        // k-window per stage, pure b128 slices
#define NSTG 45      // H_DIM / KW
#define WSTRIDE 512  // dw per wave slab in w buffer (8 rows x 64)
#define WBUF 2048    // dw per w buffer (32 rows x 64 dw)
#define REDR 36
#define LGTO 4608    // logits after red[4][32][36]
#define SMSZ 5760    // 22.5 KiB

// async global->LDS DMA, 16B/lane; dest arg per-lane = uniform base + lane*16.
#define GLD16(gp, lp)                                                  \
    __builtin_amdgcn_global_load_lds(                                  \
        (const __attribute__((address_space(1))) void*)(gp),           \
        (__attribute__((address_space(3))) void*)(lp), 16, 0, 0)

// R14: 2-stage-ahead x pipeline with counted vmcnt(8). R13 landed the rule-#20
// fix (VGPR 64->96, scratch WRITE 647MB->0.5MB, gate 447->137us) but issued
// x(s+1) at stage END and drained vmcnt(0) at next stage TOP -> zero-cover
// latency exposure every stage (VALUBusy 26%, 74% stall). Now: triple-buffer
// x (va/vb/vc named scalars), issue x(s+2) right after the barrier, wait
// vmcnt(8) -- x(s+1)'s 8 loads stay in flight ACROSS the barrier with ~2
// stages of cover (T4). Queue at stage top: [x(s):8, w(s):2, x(s+1):8].
// 45 stages = 14 uniform triples + peeled 3-stage epilogue (8/8/0).
// Skeleton otherwise = R13: TT=32, 4 waves, 8tok x 8exp/lane, 16-way k-split
// (ksd = wq*16 + ksl*4), w double-buffered in LDS via GLD16.
__global__ __attribute__((amdgpu_flat_work_group_size(256, 256),
                          amdgpu_waves_per_eu(2, 2))) void gate_fused(
    const float* __restrict__ x, const float* __restrict__ w,
    const float* __restrict__ bias, float* __restrict__ out, int T) {
    __shared__ float sm[SMSZ];
    const int tid = threadIdx.x;
    const int lane = tid & 63;
    const int wq = __builtin_amdgcn_readfirstlane(tid >> 6);
    const int tt = lane & 3;            // token group (8 tokens: tt*8..+7)
    const int et = (lane >> 2) & 3;     // expert group (8 experts: et*8..+7)
    const int ksl = lane >> 4;          // intra-wave k-slice
    const int t0 = blockIdx.x * TT;
    const int ksd = wq * 16 + ksl * 4;  // dw offset of 16B k-slice in KW window

    // w DMA: wave wq stages rows wq*8..+7 (2 instrs, 512 dw)
    const int d0 = lane * 4, d1 = 256 + lane * 4;
    const float* gw0 = w + (size_t)(wq * 8 + d0 / KW) * H_DIM + (d0 % KW);
    const float* gw1 = w + (size_t)(wq * 8 + d1 / KW) * H_DIM + (d1 % KW);
    const int lw0 = wq * WSTRIDE + d0;
    const int lw1 = wq * WSTRIDE + d1;

    // x: named per-row dword offsets from block-uniform base
    const float* xbase = x + (size_t)t0 * H_DIM;
    int xo0 = (tt * 8 + 0) * H_DIM + ksd, xo1 = (tt * 8 + 1) * H_DIM + ksd;
    int xo2 = (tt * 8 + 2) * H_DIM + ksd, xo3 = (tt * 8 + 3) * H_DIM + ksd;
    int xo4 = (tt * 8 + 4) * H_DIM + ksd, xo5 = (tt * 8 + 5) * H_DIM + ksd;
    int xo6 = (tt * 8 + 6) * H_DIM + ksd, xo7 = (tt * 8 + 7) * H_DIM + ksd;

    // acc: expert j (abs = et*8+j) -> aJl (tok 0-3), aJh (tok 4-7)
    float4 a0l = make_float4(0.f, 0.f, 0.f, 0.f), a0h = a0l, a1l = a0l, a1h = a0l;
    float4 a2l = a0l, a2h = a0l, a3l = a0l, a3h = a0l;
    float4 a4l = a0l, a4h = a0l, a5l = a0l, a5h = a0l;
    float4 a6l = a0l, a6h = a0l, a7l = a0l, a7h = a0l;
    // x triple buffer + rolling w quads -- ALL named scalars (rule #20)
    float4 va0, va1, va2, va3, va4, va5, va6, va7;
    float4 vb0, vb1, vb2, vb3, vb4, vb5, vb6, vb7;
    float4 vc0, vc1, vc2, vc3, vc4, vc5, vc6, vc7;
    float4 wA, wB;

#define SEQ asm volatile("" ::: "memory")
#define WAIT8 asm volatile("s_waitcnt vmcnt(8)" ::: "memory")
#define WAIT0 asm volatile("s_waitcnt vmcnt(0)" ::: "memory")
#define BARX                                   \
    do {                                       \
        __builtin_amdgcn_s_barrier();          \
        asm volatile("" ::: "memory");         \
    } while (0)
#define INCX                                                        \
    do {                                                            \
        xo0 += KW; xo1 += KW; xo2 += KW; xo3 += KW;                 \
        xo4 += KW; xo5 += KW; xo6 += KW; xo7 += KW;                 \
    } while (0)
#define LOADX(P)                                                    \
    do {                                                            \
        P##0 = *(const float4*)(xbase + xo0);                       \
        P##1 = *(const float4*)(xbase + xo1);                       \
        P##2 = *(const float4*)(xbase + xo2);                       \
        P##3 = *(const float4*)(xbase + xo3);                       \
        P##4 = *(const float4*)(xbase + xo4);                       \
        P##5 = *(const float4*)(xbase + xo5);                       \
        P##6 = *(const float4*)(xbase + xo6);                       \
        P##7 = *(const float4*)(xbase + xo7);                       \
    } while (0)
#define DOT(XQ, WQ) (XQ.x * WQ.x + XQ.y * WQ.y + XQ.z * WQ.z + XQ.w * WQ.w)
#define FMAE(AL, AH, WQ, P)                                         \
    do {                                                            \
        AL.x += DOT(P##0, WQ); AL.y += DOT(P##1, WQ);               \
        AL.z += DOT(P##2, WQ); AL.w += DOT(P##3, WQ);               \
        AH.x += DOT(P##4, WQ); AH.y += DOT(P##5, WQ);               \
        AH.z += DOT(P##6, WQ); AH.w += DOT(P##7, WQ);               \
    } while (0)
#define COMPUTE(P, PAR)                                             \
    do {                                                            \
        const float* wp = &sm[(PAR) * WBUF + et * (8 * KW) + ksd];  \
        wA = *(const float4*)(wp + 0 * KW);                         \
        wB = *(const float4*)(wp + 1 * KW); FMAE(a0l, a0h, wA, P);  \
        wA = *(const float4*)(wp + 2 * KW); FMAE(a1l, a1h, wB, P);  \
        wB = *(const float4*)(wp + 3 * KW); FMAE(a2l, a2h, wA, P);  \
        wA = *(const float4*)(wp + 4 * KW); FMAE(a3l, a3h, wB, P);  \
        wB = *(const float4*)(wp + 5 * KW); FMAE(a4l, a4h, wA, P);  \
        wA = *(const float4*)(wp + 6 * KW); FMAE(a5l, a5h, wB, P);  \
        wB = *(const float4*)(wp + 7 * KW); FMAE(a6l, a6h, wA, P);  \
        FMAE(a7l, a7h, wB, P);                                      \
    } while (0)
    // one full stage: wait own 10 oldest, barrier, issue w(s+1) DMA,
    // issue x(s+2) -> PNXT, compute from PCUR with w parity PAR.
#define STAGE(PCUR, PNXT, PAR)                                      \
    do {                                                            \
        WAIT8;                                                      \
        BARX;                                                       \
        GLD16(gw0, &sm[lw0 + (1 - (PAR)) * WBUF]);                  \
        GLD16(gw1, &sm[lw1 + (1 - (PAR)) * WBUF]);                  \
        gw0 += KW; gw1 += KW;                                       \
        SEQ;                                                        \
        INCX;                                                       \
        LOADX(PNXT);                                                \
        SEQ;                                                        \
        COMPUTE(PCUR, PAR);                                         \
    } while (0)

    // prologue: queue order [x(0):8, w(0):2, x(1):8]
    LOADX(va);
    SEQ;
    GLD16(gw0, &sm[lw0]); GLD16(gw1, &sm[lw1]);
    gw0 += KW; gw1 += KW;
    SEQ;
    INCX;
    LOADX(vb);
    SEQ;

    // 14 uniform triples: stages 0..41. Stage s: compute X[s%3], load X[(s+2)%3].
#pragma unroll 1
    for (int it = 0; it < 14; ++it) {
        const int p0 = it & 1, p1 = p0 ^ 1;
        STAGE(va, vc, p0);   // s = 3it
        STAGE(vb, va, p1);   // s = 3it+1
        STAGE(vc, vb, p0);   // s = 3it+2
    }
    // epilogue: stages 42 (va), 43 (vb), 44 (vc); parities 0,1,0
    WAIT8; BARX;
    GLD16(gw0, &sm[lw0 + WBUF]); GLD16(gw1, &sm[lw1 + WBUF]);  // w(43)->buf1
    gw0 += KW; gw1 += KW;
    SEQ; INCX; LOADX(vc); SEQ;          // x(44)
    COMPUTE(va, 0);
    WAIT8; BARX;
    GLD16(gw0, &sm[lw0]); GLD16(gw1, &sm[lw1]);                // w(44)->buf0
    SEQ;
    COMPUTE(vb, 1);
    WAIT0; BARX;
    COMPUTE(vc, 0);

    __syncthreads();  // all compute + DMA done; LDS repurposed

    // fold intra-wave k-slices: lanes l, l^16, l^32 share (tt,et)
#define FOLD4(V)                                                        \
    do {                                                                \
        V.x += __shfl_xor(V.x, 16, 64); V.x += __shfl_xor(V.x, 32, 64); \
        V.y += __shfl_xor(V.y, 16, 64); V.y += __shfl_xor(V.y, 32, 64); \
        V.z += __shfl_xor(V.z, 16, 64); V.z += __shfl_xor(V.z, 32, 64); \
        V.w += __shfl_xor(V.w, 16, 64); V.w += __shfl_xor(V.w, 32, 64); \
    } while (0)
    FOLD4(a0l); FOLD4(a0h); FOLD4(a1l); FOLD4(a1h);
    FOLD4(a2l); FOLD4(a2h); FOLD4(a3l); FOLD4(a3h);
    FOLD4(a4l); FOLD4(a4h); FOLD4(a5l); FOLD4(a5h);
    FOLD4(a6l); FOLD4(a6h); FOLD4(a7l); FOLD4(a7h);

    // lanes 0-15 (ksl==0) park wave partial: red[wq][tok][e] (stride 36)
    if (ksl == 0) {
#define STROW(I, HF, CP)                                                     \
    do {                                                                     \
        float* rp = &sm[wq * (TT * REDR) + (tt * 8 + I) * REDR + et * 8];    \
        *(float4*)(rp + 0) =                                                 \
            make_float4(a0##HF.CP, a1##HF.CP, a2##HF.CP, a3##HF.CP);         \
        *(float4*)(rp + 4) =                                                 \
            make_float4(a4##HF.CP, a5##HF.CP, a6##HF.CP, a7##HF.CP);         \
    } while (0)
        STROW(0, l, x); STROW(1, l, y); STROW(2, l, z); STROW(3, l, w);
        STROW(4, h, x); STROW(5, h, y); STROW(6, h, z); STROW(7, h, w);
    }
    __syncthreads();

    // sum 4 wave partials + bias: thread -> 4 logits (tok = tid>>3, e4)
    {
        const int tok = tid >> 3, e4 = (tid & 7) * 4;
        float4 sg = *(const float4*)(bias + e4);
#pragma unroll
        for (int q = 0; q < 4; ++q) {
            float4 v = *(const float4*)&sm[q * (TT * REDR) + tok * REDR + e4];
            sg.x += v.x; sg.y += v.y; sg.z += v.z; sg.w += v.w;
        }
        *(float4*)&sm[LGTO + tok * REDR + e4] = sg;
    }
    __syncthreads();

    // first 32 lanes: per-token top-4 + softmax + store
    if (tid < TT) {
        const int t = t0 + tid;
        float logit[E_NUM];
#pragma unroll
        for (int j = 0; j < 8; ++j) {
            float4 v = *(const float4*)&sm[LGTO + tid * REDR + j * 4];
            logit[j * 4] = v.x; logit[j * 4 + 1] = v.y;
            logit[j * 4 + 2] = v.z; logit[j * 4 + 3] = v.w;
        }

        // top-4 descending, ties -> lowest index (strict >, ascending scan)
        int idx[TOPK];
        float val[TOPK];
#pragma unroll
        for (int k = 0; k < TOPK; ++k) {
            float best = -INFINITY;
            int bi = 0;
#pragma unroll
            for (int e = 0; e < E_NUM; ++e) {
                bool taken = false;
                for (int p2 = 0; p2 < k; ++p2) taken = taken || (idx[p2] == e);
                float v = logit[e];
                if (!taken && v > best) { best = v; bi = e; }
            }
            idx[k] = bi;
            val[k] = best;
        }
        float ex[TOPK], ssum = 0.f;
#pragma unroll
        for (int k = 0; k < TOPK; ++k) { ex[k] = expf(val[k] - val[0]); ssum += ex[k]; }
        const float inv = 1.f / ssum;

        *(float4*)(out + (size_t)t * 4) =
            make_float4((float)idx[0], (float)idx[1], (float)idx[2], (float)idx[3]);
        *(float4*)(out + (size_t)T * 4 + (size_t)t * 4) =
            make_float4(ex[0] * inv, ex[1] * inv, ex[2] * inv, ex[3] * inv);
    }
}

extern "C" void kernel_launch(void* const* d_in, const int* in_sizes, int n_in,
                              void* d_out, int out_size, void* d_ws, size_t ws_size,
                              hipStream_t stream) {
    const float* x    = (const float*)d_in[0];  // [B,S,H] fp32
    const float* w    = (const float*)d_in[1];  // [E,H] fp32
    const float* bias = (const float*)d_in[2];  // [E] fp32
    float* out = (float*)d_out;

    const int T = in_sizes[0] / H_DIM;  // 16384

    gate_fused<<<dim3(T / TT), 256, 0, stream>>>(x, w, bias, out, T);
}